// Round 10
// baseline (330.700 us; speedup 1.0000x reference)
//
#include <hip/hip_runtime.h>
#include <hip/hip_bf16.h>

// ---- problem constants ----
constexpr int BB  = 256;   // batch
constexpr int TT  = 1024;  // timesteps
constexpr int DXc = 64;
constexpr int DZc = 128;
constexpr int DBc = 16;
constexpr int TAUc = 25;
constexpr float CLIPV = 10.0f;
constexpr int NF = 40;     // forcing steps: t = 25..1000
constexpr int NSEG = 41;   // independent scan segments (forcing breaks chain)
constexpr int GRP = 8;     // batch rows per scan block (half-filled MFMA N)
constexpr int NGRP = BB / GRP;   // 32 row groups

typedef __attribute__((ext_vector_type(8))) short short8;        // 8 bf16
typedef __attribute__((ext_vector_type(8))) _Float16 half8;      // 8 f16
typedef __attribute__((ext_vector_type(4))) float f32x4;
typedef __attribute__((ext_vector_type(4))) unsigned u32x4;
typedef __attribute__((ext_vector_type(2))) unsigned u32x2;

__device__ __forceinline__ unsigned perm_b32(unsigned a, unsigned b, unsigned s) {
  return __builtin_amdgcn_perm(a, b, s);
}

// pack 8 floats into bf16 hi + residual-lo short8 frags (W staging)
__device__ __forceinline__ void pack_hilo8(const f32x4 a, const f32x4 b,
                                           short8& hi, short8& lo) {
  float f[8];
  *(f32x4*)&f[0] = a;
  *(f32x4*)&f[4] = b;
  u32x4 hi4, lo4;
  #pragma unroll
  for (int p = 0; p < 4; ++p) {
    const unsigned b0 = __float_as_uint(f[2 * p]);
    const unsigned b1 = __float_as_uint(f[2 * p + 1]);
    hi4[p] = perm_b32(b1, b0, 0x07060302u);
    const float l0 = f[2 * p]     - __uint_as_float(b0 & 0xFFFF0000u);
    const float l1 = f[2 * p + 1] - __uint_as_float(b1 & 0xFFFF0000u);
    lo4[p] = perm_b32(__float_as_uint(l1), __float_as_uint(l0), 0x07060302u);
  }
  hi = __builtin_bit_cast(short8, hi4);
  lo = __builtin_bit_cast(short8, lo4);
}

// 8 floats -> f16 frag (RNE, single precision pass)
__device__ __forceinline__ half8 cvt8_f16(const f32x4 a, const f32x4 b) {
  float f[8];
  *(f32x4*)&f[0] = a;
  *(f32x4*)&f[4] = b;
  u32x4 h4;
  #pragma unroll
  for (int p = 0; p < 4; ++p) {
    const _Float16 h0 = (_Float16)f[2 * p], h1 = (_Float16)f[2 * p + 1];
    h4[p] = (unsigned)__builtin_bit_cast(unsigned short, h0)
          | ((unsigned)__builtin_bit_cast(unsigned short, h1) << 16);
  }
  return __builtin_bit_cast(half8, h4);
}

// 8 floats -> f16 hi + f16 residual frags
__device__ __forceinline__ void cvt8_f16_hilo(const f32x4 a, const f32x4 b,
                                              half8& hi, half8& lo) {
  float f[8];
  *(f32x4*)&f[0] = a;
  *(f32x4*)&f[4] = b;
  u32x4 h4, l4;
  #pragma unroll
  for (int p = 0; p < 4; ++p) {
    const float f0 = f[2 * p], f1 = f[2 * p + 1];
    const _Float16 h0 = (_Float16)f0, h1 = (_Float16)f1;
    const float r0 = f0 - (float)h0, r1 = f1 - (float)h1;
    const _Float16 e0 = (_Float16)r0, e1 = (_Float16)r1;
    h4[p] = (unsigned)__builtin_bit_cast(unsigned short, h0)
          | ((unsigned)__builtin_bit_cast(unsigned short, h1) << 16);
    l4[p] = (unsigned)__builtin_bit_cast(unsigned short, e0)
          | ((unsigned)__builtin_bit_cast(unsigned short, e1) << 16);
  }
  hi = __builtin_bit_cast(half8, h4);
  lo = __builtin_bit_cast(half8, l4);
}

__device__ __forceinline__ unsigned pk2_f16(float a, float b) {
  const _Float16 ha = (_Float16)a, hb = (_Float16)b;
  return (unsigned)__builtin_bit_cast(unsigned short, ha)
       | ((unsigned)__builtin_bit_cast(unsigned short, hb) << 16);
}

// f32x4 -> f16 hi pair-words + f16 residual pair-words
__device__ __forceinline__ void pk4_f16_hilo(const f32x4 v, u32x2& hi, u32x2& lo) {
  const _Float16 h0 = (_Float16)v[0], h1 = (_Float16)v[1];
  const _Float16 h2 = (_Float16)v[2], h3 = (_Float16)v[3];
  const float r0 = v[0] - (float)h0, r1 = v[1] - (float)h1;
  const float r2 = v[2] - (float)h2, r3 = v[3] - (float)h3;
  hi[0] = (unsigned)__builtin_bit_cast(unsigned short, h0)
        | ((unsigned)__builtin_bit_cast(unsigned short, h1) << 16);
  hi[1] = (unsigned)__builtin_bit_cast(unsigned short, h2)
        | ((unsigned)__builtin_bit_cast(unsigned short, h3) << 16);
  lo[0] = pk2_f16(r0, r1);
  lo[1] = pk2_f16(r2, r3);
}

// fast tanh: 1 - 2/(1+exp2(2x*log2e)), copysign. ~6 VALU, ~1e-6 rel err.
__device__ __forceinline__ float ftanh(float x) {
  const float ax = __builtin_fabsf(x);
  const float p  = __builtin_amdgcn_exp2f(ax * 2.8853900817779268f);
  const float r  = __builtin_amdgcn_rcpf(p + 1.0f);
  const float t  = __builtin_fmaf(-2.0f, r, 1.0f);
  return __builtin_copysignf(t, x);
}

__device__ __forceinline__ float sload(const float* p) {
  return __uint_as_float(__builtin_amdgcn_readfirstlane(__float_as_uint(*p)));
}

#define SCAN_BAR() do { \
    __asm__ volatile("s_waitcnt lgkmcnt(0)" ::: "memory"); \
    __builtin_amdgcn_s_barrier(); \
    __asm__ volatile("" ::: "memory"); } while (0)

// =====================================================================
// Encoder (MFMA): unchanged (validated).
// =====================================================================
constexpr int ENC_NT = 4;

__global__ __launch_bounds__(256, 2) void enc_mfma_kernel(
    const float* __restrict__ x, const float* __restrict__ w1,
    const float* __restrict__ b1v, const float* __restrict__ w2,
    const float* __restrict__ b2v, float* __restrict__ zs)
{
  const int tid = threadIdx.x;
  const int w = tid >> 6, l = tid & 63;
  const int rowf = l & 15;
  const int kg = l >> 4;

  __shared__ unsigned hb[2][16][68];

  half8 W1f[2][2], W2f[2][4];
  #pragma unroll
  for (int tm = 0; tm < 2; ++tm) {
    const int m = (2 * w + tm) * 16 + rowf;
    #pragma unroll
    for (int kt = 0; kt < 2; ++kt) {             // K = 64
      const int k0 = kt * 32 + kg * 8;
      W1f[tm][kt] = cvt8_f16(*(const f32x4*)&w1[m * DXc + k0],
                             *(const f32x4*)&w1[m * DXc + k0 + 4]);
    }
    #pragma unroll
    for (int kt = 0; kt < 4; ++kt) {             // K = 128
      const int k0 = kt * 32 + kg * 8;
      W2f[tm][kt] = cvt8_f16(*(const f32x4*)&w2[m * DZc + k0],
                             *(const f32x4*)&w2[m * DZc + k0 + 4]);
    }
  }
  float b1r[2][4], b2r[2][4];
  #pragma unroll
  for (int tm = 0; tm < 2; ++tm)
    #pragma unroll
    for (int j = 0; j < 4; ++j) {
      b1r[tm][j] = b1v[(2 * w + tm) * 16 + kg * 4 + j];
      b2r[tm][j] = b2v[(2 * w + tm) * 16 + kg * 4 + j];
    }

  for (int it = 0; it < ENC_NT; ++it) {
    const int r = blockIdx.x * (ENC_NT * 16) + it * 16 + rowf;
    const int f = r >> 8, b = r & 255;
    const int t = TAUc * (f + 1);
    const float* xr = x + ((size_t)b * TT + t) * DXc + kg * 8;

    f32x4 aH0 = {b1r[0][0], b1r[0][1], b1r[0][2], b1r[0][3]};
    f32x4 aH1 = {b1r[1][0], b1r[1][1], b1r[1][2], b1r[1][3]};
    f32x4 aL0 = {0.f, 0.f, 0.f, 0.f}, aL1 = {0.f, 0.f, 0.f, 0.f};
    #pragma unroll
    for (int kt = 0; kt < 2; ++kt) {
      half8 xh, xl;
      cvt8_f16_hilo(*(const f32x4*)&xr[kt * 32], *(const f32x4*)&xr[kt * 32 + 4],
                    xh, xl);
      aH0 = __builtin_amdgcn_mfma_f32_16x16x32_f16(W1f[0][kt], xh, aH0, 0, 0, 0);
      aH1 = __builtin_amdgcn_mfma_f32_16x16x32_f16(W1f[1][kt], xh, aH1, 0, 0, 0);
      aL0 = __builtin_amdgcn_mfma_f32_16x16x32_f16(W1f[0][kt], xl, aL0, 0, 0, 0);
      aL1 = __builtin_amdgcn_mfma_f32_16x16x32_f16(W1f[1][kt], xl, aL1, 0, 0, 0);
    }
    {
      u32x2 pk0, pk1;
      pk0[0] = pk2_f16(ftanh(aH0[0] + aL0[0]), ftanh(aH0[1] + aL0[1]));
      pk0[1] = pk2_f16(ftanh(aH0[2] + aL0[2]), ftanh(aH0[3] + aL0[3]));
      pk1[0] = pk2_f16(ftanh(aH1[0] + aL1[0]), ftanh(aH1[1] + aL1[1]));
      pk1[1] = pk2_f16(ftanh(aH1[2] + aL1[2]), ftanh(aH1[3] + aL1[3]));
      *(u32x2*)&hb[it & 1][rowf][(2 * w + 0) * 8 + kg * 2] = pk0;
      *(u32x2*)&hb[it & 1][rowf][(2 * w + 1) * 8 + kg * 2] = pk1;
    }
    SCAN_BAR();

    #pragma unroll
    for (int tm = 0; tm < 2; ++tm) {
      f32x4 a2 = {b2r[tm][0], b2r[tm][1], b2r[tm][2], b2r[tm][3]};
      #pragma unroll
      for (int kt = 0; kt < 4; ++kt) {
        const u32x4 hp = *(const u32x4*)&hb[it & 1][rowf][kt * 16 + kg * 4];
        a2 = __builtin_amdgcn_mfma_f32_16x16x32_f16(W2f[tm][kt],
                 __builtin_bit_cast(half8, hp), a2, 0, 0, 0);
      }
      f32x4 ov;
      #pragma unroll
      for (int j = 0; j < 4; ++j) ov[j] = ftanh(a2[j]);
      *(f32x4*)&zs[((size_t)b * TT + t) * DZc + (2 * w + tm) * 16 + kg * 4] = ov;
    }
  }
}

// =====================================================================
// Fused scan+decoder v3 (R10): R8 structure/mapping (validated, no
// setprio), but GRP=8 -> grid 1312 (~5 blk/CU, 2x TLP). MFMA tiles run
// half-filled (rows 8..15 duplicate rows 0..7 via rowf&7 read-clamps);
// per-block VALU halves (basis: 4 rows/lane; publishes/stores masked
// to rowf<8) so chip-wide VALU stays ~flat while stall-filling doubles.
// alphas in SGPRs. LDS ~17 KB.
// =====================================================================
__global__ __launch_bounds__(256, 1) void scan_dec_kernel(
    const float* __restrict__ AW, const float* __restrict__ z0,
    const float* __restrict__ hvec, const float* __restrict__ alphas,
    const float* __restrict__ thetas,
    const float* __restrict__ dw1, const float* __restrict__ db1,
    const float* __restrict__ dw2, const float* __restrict__ db2,
    float* __restrict__ zs, float* __restrict__ xp)
{
  const int bid = blockIdx.x;
  const int g = bid & (NGRP - 1);          // row group (32 groups of 8)
  const int s = bid >> 5;                  // segment 0..40
  const int t0 = s * TAUc;
  const int nsteps = (s == NSEG - 1) ? (TT - t0) : TAUc;

  const int tid = threadIdx.x;
  const int w = tid >> 6, l = tid & 63;
  const int rowf = l & 15;                 // MFMA N index (0..15)
  const int rv = rowf & 7;                 // valid-row clamp
  const bool valid = (rowf < 8);
  const int kg = l >> 4;

  __shared__ float zbuf[DZc][12];          // [comp][row<8], pitch 12 (16B-align)
  __shared__ float meanp[8][4];
  __shared__ unsigned pbuf[8][DZc + 4];    // basis packed bf16, pitch 132
  __shared__ unsigned zpkh[8][68];         // z f16 hi pairs
  __shared__ unsigned zpkl[8][68];         // z f16 lo pairs
  __shared__ unsigned hbuf[8][68];         // dec hidden f16 pairs

  // ---- recurrence stationary: W bf16 hi/lo frags, diag, h ----
  short8 Whi[2][4], Wlo[2][4];
  #pragma unroll
  for (int tm = 0; tm < 2; ++tm) {
    const int m = (2 * w + tm) * 16 + rowf;
    #pragma unroll
    for (int kt = 0; kt < 4; ++kt) {
      const int kb = kt * 32 + kg * 8;
      float f[8];
      #pragma unroll
      for (int i = 0; i < 8; ++i) {
        const int k = kb + i;
        f[i] = (k == m) ? 0.f : AW[m * DZc + k];
      }
      pack_hilo8(*(const f32x4*)&f[0], *(const f32x4*)&f[4],
                 Whi[tm][kt], Wlo[tm][kt]);
    }
  }
  float a_d[2][4], h_d[2][4];
  #pragma unroll
  for (int tm = 0; tm < 2; ++tm)
    #pragma unroll
    for (int j = 0; j < 4; ++j) {
      const int comp = (2 * w + tm) * 16 + kg * 4 + j;
      a_d[tm][j] = AW[comp * DZc + comp];
      h_d[tm][j] = hvec[comp];
    }

  // ---- decoder stationary: f16 weights ----
  half8 D1f[2][4], D2f[4];
  #pragma unroll
  for (int tm = 0; tm < 2; ++tm) {
    const int m = (2 * w + tm) * 16 + rowf;
    #pragma unroll
    for (int kt = 0; kt < 4; ++kt) {
      const int k0 = kt * 32 + kg * 8;
      D1f[tm][kt] = cvt8_f16(*(const f32x4*)&dw1[m * DZc + k0],
                             *(const f32x4*)&dw1[m * DZc + k0 + 4]);
    }
  }
  {
    const int m2 = w * 16 + rowf;
    #pragma unroll
    for (int kt = 0; kt < 4; ++kt) {
      const int k0 = kt * 32 + kg * 8;
      D2f[kt] = cvt8_f16(*(const f32x4*)&dw2[m2 * DZc + k0],
                         *(const f32x4*)&dw2[m2 * DZc + k0 + 4]);
    }
  }
  float d1b[2][4], d2b[4];
  #pragma unroll
  for (int tm = 0; tm < 2; ++tm)
    #pragma unroll
    for (int j = 0; j < 4; ++j)
      d1b[tm][j] = db1[(2 * w + tm) * 16 + kg * 4 + j];
  #pragma unroll
  for (int j = 0; j < 4; ++j)
    d2b[j] = db2[w * 16 + kg * 4 + j];

  // ---- basis-lane stationary: comp cb, rows rh*4..+3 (4 rows) ----
  const int cb = tid >> 1;                 // comp 0..127
  const int rh = tid & 1;                  // row half (of 8)
  float th[DBc], al[DBc];
  #pragma unroll
  for (int d = 0; d < DBc; ++d) {
    th[d] = thetas[cb * DBc + d];
    al[d] = sload(&alphas[d]);             // uniform -> SGPR
  }

  const int brow = g * GRP + rv;           // valid batch row (dup for rowf>=8)
  const size_t zb_row = (size_t)brow * TT * DZc;
  const size_t xp_row = (size_t)brow * TT * DXc;
  f32x4 z[2];
  #pragma unroll
  for (int tm = 0; tm < 2; ++tm) {
    const int comp0 = (2 * w + tm) * 16 + kg * 4;
    f32x4 zi;
    if (s == 0) zi = *(const f32x4*)&z0[brow * DZc + comp0];
    else        zi = *(const f32x4*)&zs[zb_row + (size_t)t0 * DZc + comp0];
    z[tm] = valid ? zi : f32x4{0.f, 0.f, 0.f, 0.f};
  }

#define PUB_ZPK() do { \
    if (valid) { \
      _Pragma("unroll") \
      for (int tm = 0; tm < 2; ++tm) { \
        u32x2 zh_, zl_; \
        pk4_f16_hilo(z[tm], zh_, zl_); \
        *(u32x2*)&zpkh[rv][(2 * w + tm) * 8 + kg * 2] = zh_; \
        *(u32x2*)&zpkl[rv][(2 * w + tm) * 8 + kg * 2] = zl_; \
      } \
    } } while (0)

#define DEC_L1() do { \
    f32x4 dAh = {d1b[0][0], d1b[0][1], d1b[0][2], d1b[0][3]}; \
    f32x4 dBh = {d1b[1][0], d1b[1][1], d1b[1][2], d1b[1][3]}; \
    f32x4 dAl = {0.f, 0.f, 0.f, 0.f}, dBl = {0.f, 0.f, 0.f, 0.f}; \
    _Pragma("unroll") \
    for (int kt = 0; kt < 4; ++kt) { \
      const u32x4 bh = *(const u32x4*)&zpkh[rv][kt * 16 + kg * 4]; \
      const u32x4 bl = *(const u32x4*)&zpkl[rv][kt * 16 + kg * 4]; \
      const half8 Bh = __builtin_bit_cast(half8, bh); \
      const half8 Bl = __builtin_bit_cast(half8, bl); \
      dAh = __builtin_amdgcn_mfma_f32_16x16x32_f16(D1f[0][kt], Bh, dAh, 0, 0, 0); \
      dBh = __builtin_amdgcn_mfma_f32_16x16x32_f16(D1f[1][kt], Bh, dBh, 0, 0, 0); \
      dAl = __builtin_amdgcn_mfma_f32_16x16x32_f16(D1f[0][kt], Bl, dAl, 0, 0, 0); \
      dBl = __builtin_amdgcn_mfma_f32_16x16x32_f16(D1f[1][kt], Bl, dBl, 0, 0, 0); \
    } \
    if (valid) { \
      u32x2 pk0, pk1; \
      pk0[0] = pk2_f16(ftanh(dAh[0] + dAl[0]), ftanh(dAh[1] + dAl[1])); \
      pk0[1] = pk2_f16(ftanh(dAh[2] + dAl[2]), ftanh(dAh[3] + dAl[3])); \
      pk1[0] = pk2_f16(ftanh(dBh[0] + dBl[0]), ftanh(dBh[1] + dBl[1])); \
      pk1[1] = pk2_f16(ftanh(dBh[2] + dBl[2]), ftanh(dBh[3] + dBl[3])); \
      *(u32x2*)&hbuf[rv][(2 * w + 0) * 8 + kg * 2] = pk0; \
      *(u32x2*)&hbuf[rv][(2 * w + 1) * 8 + kg * 2] = pk1; \
    } } while (0)

#define DEC_L2(TD) do { \
    f32x4 a2 = {d2b[0], d2b[1], d2b[2], d2b[3]}; \
    _Pragma("unroll") \
    for (int kt = 0; kt < 4; ++kt) { \
      const u32x4 hp = *(const u32x4*)&hbuf[rv][kt * 16 + kg * 4]; \
      a2 = __builtin_amdgcn_mfma_f32_16x16x32_f16(D2f[kt], \
               __builtin_bit_cast(half8, hp), a2, 0, 0, 0); \
    } \
    if (valid) { \
      f32x4 ov; \
      _Pragma("unroll") \
      for (int j = 0; j < 4; ++j) ov[j] = ftanh(a2[j]); \
      *(f32x4*)&xp[xp_row + (size_t)(TD) * DXc + w * 16 + kg * 4] = ov; \
    } } while (0)

  for (int it = 0; it < nsteps; ++it) {
    const int t = t0 + it;

    // ---- Phase A: publish z (valid rows only) ----
    float ssum = ((z[0][0] + z[0][1]) + (z[0][2] + z[0][3]))
               + ((z[1][0] + z[1][1]) + (z[1][2] + z[1][3]));
    ssum += __shfl_xor(ssum, 16, 64);
    ssum += __shfl_xor(ssum, 32, 64);      // wave partial for row rowf
    if (l < 8) meanp[l][w] = ssum;
    if (valid) {
      #pragma unroll
      for (int tm = 0; tm < 2; ++tm)
        #pragma unroll
        for (int j = 0; j < 4; ++j)
          zbuf[(2 * w + tm) * 16 + kg * 4 + j][rv] = z[tm][j];
    }
    PUB_ZPK();
    SCAN_BAR();

    // ---- Phase B: basis (comp cb, 4 rows) + decode-L1 (z_seq[t-1]) ----
    {
      float zr[4], mean[4];
      *(f32x4*)&zr[0] = *(const f32x4*)&zbuf[cb][rh * 4];
      #pragma unroll
      for (int q = 0; q < 4; ++q) {
        const f32x4 mp = *(const f32x4*)&meanp[rh * 4 + q][0];
        mean[q] = ((mp[0] + mp[1]) + (mp[2] + mp[3])) * (1.0f / 128.0f);
      }
      #pragma unroll
      for (int q = 0; q < 4; ++q) {
        const float zc = zr[q] - mean[q];
        float bs = 0.f;
        #pragma unroll
        for (int d = 0; d < DBc; ++d)
          bs = fmaf(al[d], fmaxf(zc + th[d], 0.f), bs);
        const unsigned fb = __float_as_uint(bs);
        const float lof = bs - __uint_as_float(fb & 0xFFFF0000u);
        const unsigned pk = perm_b32(__float_as_uint(lof), fb, 0x07060302u);
        pbuf[rh * 4 + q][cb] = pk;
      }
    }
    if (it > 0) DEC_L1();
    SCAN_BAR();

    // ---- Phase C: decode-L2 + recurrence ----
    if (it > 0) DEC_L2(t - 1);
    {
      f32x4 acc1[2], acc2[2];
      #pragma unroll
      for (int tm = 0; tm < 2; ++tm)
        #pragma unroll
        for (int j = 0; j < 4; ++j) {
          acc1[tm][j] = fmaf(a_d[tm][j], z[tm][j], h_d[tm][j]);
          acc2[tm][j] = 0.f;
        }
      #pragma unroll
      for (int kt = 0; kt < 4; ++kt) {
        const int cbase = kt * 32 + kg * 8;
        const u32x4 p0 = *(const u32x4*)&pbuf[rv][cbase];
        const u32x4 p1 = *(const u32x4*)&pbuf[rv][cbase + 4];
        u32x4 hi4, lo4;
        hi4[0] = perm_b32(p0[1], p0[0], 0x05040100u);
        hi4[1] = perm_b32(p0[3], p0[2], 0x05040100u);
        hi4[2] = perm_b32(p1[1], p1[0], 0x05040100u);
        hi4[3] = perm_b32(p1[3], p1[2], 0x05040100u);
        lo4[0] = perm_b32(p0[1], p0[0], 0x07060302u);
        lo4[1] = perm_b32(p0[3], p0[2], 0x07060302u);
        lo4[2] = perm_b32(p1[1], p1[0], 0x07060302u);
        lo4[3] = perm_b32(p1[3], p1[2], 0x07060302u);
        const short8 Bhi = __builtin_bit_cast(short8, hi4);
        const short8 Blo = __builtin_bit_cast(short8, lo4);
        acc1[0] = __builtin_amdgcn_mfma_f32_16x16x32_bf16(Whi[0][kt], Bhi, acc1[0], 0, 0, 0);
        acc1[1] = __builtin_amdgcn_mfma_f32_16x16x32_bf16(Whi[1][kt], Bhi, acc1[1], 0, 0, 0);
        acc2[0] = __builtin_amdgcn_mfma_f32_16x16x32_bf16(Whi[0][kt], Blo, acc2[0], 0, 0, 0);
        acc2[0] = __builtin_amdgcn_mfma_f32_16x16x32_bf16(Wlo[0][kt], Bhi, acc2[0], 0, 0, 0);
        acc2[1] = __builtin_amdgcn_mfma_f32_16x16x32_bf16(Whi[1][kt], Blo, acc2[1], 0, 0, 0);
        acc2[1] = __builtin_amdgcn_mfma_f32_16x16x32_bf16(Wlo[1][kt], Bhi, acc2[1], 0, 0, 0);
      }
      #pragma unroll
      for (int tm = 0; tm < 2; ++tm) {
        f32x4 zn;
        #pragma unroll
        for (int j = 0; j < 4; ++j) {
          float v = acc1[tm][j] + acc2[tm][j];
          zn[j] = fminf(fmaxf(v, -CLIPV), CLIPV);
        }
        if (valid)
          *(f32x4*)&zs[zb_row + (size_t)t * DZc + (2 * w + tm) * 16 + kg * 4] = zn;
        z[tm] = zn;
      }
    }
  }

  // ---- epilogue: decode the segment's final z_seq ----
  PUB_ZPK();
  SCAN_BAR();
  DEC_L1();
  SCAN_BAR();
  DEC_L2(t0 + nsteps - 1);

#undef PUB_ZPK
#undef DEC_L1
#undef DEC_L2
}

extern "C" void kernel_launch(void* const* d_in, const int* in_sizes, int n_in,
                              void* d_out, int out_size, void* d_ws, size_t ws_size,
                              hipStream_t stream) {
  const float* x      = (const float*)d_in[0];
  const float* z0     = (const float*)d_in[1];
  const float* AW     = (const float*)d_in[2];
  const float* hvec   = (const float*)d_in[3];
  const float* alphas = (const float*)d_in[4];
  const float* thetas = (const float*)d_in[5];
  const float* ew1    = (const float*)d_in[6];
  const float* eb1    = (const float*)d_in[7];
  const float* ew2    = (const float*)d_in[8];
  const float* eb2    = (const float*)d_in[9];
  const float* dw1    = (const float*)d_in[10];
  const float* db1    = (const float*)d_in[11];
  const float* dw2    = (const float*)d_in[12];
  const float* db2    = (const float*)d_in[13];

  float* xp = (float*)d_out;                       // (B,T,DX)
  float* zs = xp + (size_t)BB * TT * DXc;          // (B,T,DZ)

  // 1) MFMA encoder: 40 forcing steps -> stash into zs slots
  hipLaunchKernelGGL(enc_mfma_kernel,
                     dim3(NF * BB / (ENC_NT * 16)), dim3(256), 0, stream,
                     x, ew1, eb1, ew2, eb2, zs);

  // 2) fused scan + decoder: 32 row-groups x 41 segments = 1312 blocks
  hipLaunchKernelGGL(scan_dec_kernel, dim3(NGRP * NSEG), dim3(256), 0, stream,
                     AW, z0, hvec, alphas, thetas, dw1, db1, dw2, db2, zs, xp);
}

// Round 11
// 200.105 us; speedup vs baseline: 1.6526x; 1.6526x over previous
//
#include <hip/hip_runtime.h>
#include <hip/hip_bf16.h>

// ---- problem constants ----
constexpr int BB  = 256;   // batch
constexpr int TT  = 1024;  // timesteps
constexpr int DXc = 64;
constexpr int DZc = 128;
constexpr int DBc = 16;
constexpr int TAUc = 25;
constexpr float CLIPV = 10.0f;
constexpr int NF = 40;     // forcing steps: t = 25..1000
constexpr int NSEG = 41;   // independent scan segments (forcing breaks chain)
constexpr int GRP = 16;    // batch rows per scan block (MFMA N dim)

typedef __attribute__((ext_vector_type(8))) short short8;        // 8 bf16
typedef __attribute__((ext_vector_type(8))) _Float16 half8;      // 8 f16
typedef __attribute__((ext_vector_type(4))) float f32x4;
typedef __attribute__((ext_vector_type(2))) float f32x2;
typedef __attribute__((ext_vector_type(4))) unsigned u32x4;
typedef __attribute__((ext_vector_type(2))) unsigned u32x2;

__device__ __forceinline__ unsigned perm_b32(unsigned a, unsigned b, unsigned s) {
  return __builtin_amdgcn_perm(a, b, s);
}

// pack 8 floats into bf16 hi + residual-lo short8 frags (W staging)
__device__ __forceinline__ void pack_hilo8(const f32x4 a, const f32x4 b,
                                           short8& hi, short8& lo) {
  float f[8];
  *(f32x4*)&f[0] = a;
  *(f32x4*)&f[4] = b;
  u32x4 hi4, lo4;
  #pragma unroll
  for (int p = 0; p < 4; ++p) {
    const unsigned b0 = __float_as_uint(f[2 * p]);
    const unsigned b1 = __float_as_uint(f[2 * p + 1]);
    hi4[p] = perm_b32(b1, b0, 0x07060302u);
    const float l0 = f[2 * p]     - __uint_as_float(b0 & 0xFFFF0000u);
    const float l1 = f[2 * p + 1] - __uint_as_float(b1 & 0xFFFF0000u);
    lo4[p] = perm_b32(__float_as_uint(l1), __float_as_uint(l0), 0x07060302u);
  }
  hi = __builtin_bit_cast(short8, hi4);
  lo = __builtin_bit_cast(short8, lo4);
}

// 8 floats -> f16 frag (RNE, single precision pass)
__device__ __forceinline__ half8 cvt8_f16(const f32x4 a, const f32x4 b) {
  float f[8];
  *(f32x4*)&f[0] = a;
  *(f32x4*)&f[4] = b;
  u32x4 h4;
  #pragma unroll
  for (int p = 0; p < 4; ++p) {
    const _Float16 h0 = (_Float16)f[2 * p], h1 = (_Float16)f[2 * p + 1];
    h4[p] = (unsigned)__builtin_bit_cast(unsigned short, h0)
          | ((unsigned)__builtin_bit_cast(unsigned short, h1) << 16);
  }
  return __builtin_bit_cast(half8, h4);
}

// 8 floats -> f16 hi + f16 residual frags
__device__ __forceinline__ void cvt8_f16_hilo(const f32x4 a, const f32x4 b,
                                              half8& hi, half8& lo) {
  float f[8];
  *(f32x4*)&f[0] = a;
  *(f32x4*)&f[4] = b;
  u32x4 h4, l4;
  #pragma unroll
  for (int p = 0; p < 4; ++p) {
    const float f0 = f[2 * p], f1 = f[2 * p + 1];
    const _Float16 h0 = (_Float16)f0, h1 = (_Float16)f1;
    const float r0 = f0 - (float)h0, r1 = f1 - (float)h1;
    const _Float16 e0 = (_Float16)r0, e1 = (_Float16)r1;
    h4[p] = (unsigned)__builtin_bit_cast(unsigned short, h0)
          | ((unsigned)__builtin_bit_cast(unsigned short, h1) << 16);
    l4[p] = (unsigned)__builtin_bit_cast(unsigned short, e0)
          | ((unsigned)__builtin_bit_cast(unsigned short, e1) << 16);
  }
  hi = __builtin_bit_cast(half8, h4);
  lo = __builtin_bit_cast(half8, l4);
}

__device__ __forceinline__ unsigned pk2_f16(float a, float b) {
  const _Float16 ha = (_Float16)a, hb = (_Float16)b;
  return (unsigned)__builtin_bit_cast(unsigned short, ha)
       | ((unsigned)__builtin_bit_cast(unsigned short, hb) << 16);
}

// f32x4 -> f16 hi pair-words + f16 residual pair-words
__device__ __forceinline__ void pk4_f16_hilo(const f32x4 v, u32x2& hi, u32x2& lo) {
  const _Float16 h0 = (_Float16)v[0], h1 = (_Float16)v[1];
  const _Float16 h2 = (_Float16)v[2], h3 = (_Float16)v[3];
  const float r0 = v[0] - (float)h0, r1 = v[1] - (float)h1;
  const float r2 = v[2] - (float)h2, r3 = v[3] - (float)h3;
  hi[0] = (unsigned)__builtin_bit_cast(unsigned short, h0)
        | ((unsigned)__builtin_bit_cast(unsigned short, h1) << 16);
  hi[1] = (unsigned)__builtin_bit_cast(unsigned short, h2)
        | ((unsigned)__builtin_bit_cast(unsigned short, h3) << 16);
  lo[0] = pk2_f16(r0, r1);
  lo[1] = pk2_f16(r2, r3);
}

// fast tanh: 1 - 2/(1+exp2(2x*log2e)), copysign. ~6 VALU, ~1e-6 rel err.
__device__ __forceinline__ float ftanh(float x) {
  const float ax = __builtin_fabsf(x);
  const float p  = __builtin_amdgcn_exp2f(ax * 2.8853900817779268f);
  const float r  = __builtin_amdgcn_rcpf(p + 1.0f);
  const float t  = __builtin_fmaf(-2.0f, r, 1.0f);
  return __builtin_copysignf(t, x);
}

__device__ __forceinline__ float sload(const float* p) {
  return __uint_as_float(__builtin_amdgcn_readfirstlane(__float_as_uint(*p)));
}

#define SCAN_BAR() do { \
    __asm__ volatile("s_waitcnt lgkmcnt(0)" ::: "memory"); \
    __builtin_amdgcn_s_barrier(); \
    __asm__ volatile("" ::: "memory"); } while (0)

// =====================================================================
// Encoder (MFMA): unchanged (validated).
// =====================================================================
constexpr int ENC_NT = 4;

__global__ __launch_bounds__(256, 2) void enc_mfma_kernel(
    const float* __restrict__ x, const float* __restrict__ w1,
    const float* __restrict__ b1v, const float* __restrict__ w2,
    const float* __restrict__ b2v, float* __restrict__ zs)
{
  const int tid = threadIdx.x;
  const int w = tid >> 6, l = tid & 63;
  const int rowf = l & 15;
  const int kg = l >> 4;

  __shared__ unsigned hb[2][16][68];

  half8 W1f[2][2], W2f[2][4];
  #pragma unroll
  for (int tm = 0; tm < 2; ++tm) {
    const int m = (2 * w + tm) * 16 + rowf;
    #pragma unroll
    for (int kt = 0; kt < 2; ++kt) {             // K = 64
      const int k0 = kt * 32 + kg * 8;
      W1f[tm][kt] = cvt8_f16(*(const f32x4*)&w1[m * DXc + k0],
                             *(const f32x4*)&w1[m * DXc + k0 + 4]);
    }
    #pragma unroll
    for (int kt = 0; kt < 4; ++kt) {             // K = 128
      const int k0 = kt * 32 + kg * 8;
      W2f[tm][kt] = cvt8_f16(*(const f32x4*)&w2[m * DZc + k0],
                             *(const f32x4*)&w2[m * DZc + k0 + 4]);
    }
  }
  float b1r[2][4], b2r[2][4];
  #pragma unroll
  for (int tm = 0; tm < 2; ++tm)
    #pragma unroll
    for (int j = 0; j < 4; ++j) {
      b1r[tm][j] = b1v[(2 * w + tm) * 16 + kg * 4 + j];
      b2r[tm][j] = b2v[(2 * w + tm) * 16 + kg * 4 + j];
    }

  for (int it = 0; it < ENC_NT; ++it) {
    const int r = blockIdx.x * (ENC_NT * 16) + it * 16 + rowf;
    const int f = r >> 8, b = r & 255;
    const int t = TAUc * (f + 1);
    const float* xr = x + ((size_t)b * TT + t) * DXc + kg * 8;

    f32x4 aH0 = {b1r[0][0], b1r[0][1], b1r[0][2], b1r[0][3]};
    f32x4 aH1 = {b1r[1][0], b1r[1][1], b1r[1][2], b1r[1][3]};
    f32x4 aL0 = {0.f, 0.f, 0.f, 0.f}, aL1 = {0.f, 0.f, 0.f, 0.f};
    #pragma unroll
    for (int kt = 0; kt < 2; ++kt) {
      half8 xh, xl;
      cvt8_f16_hilo(*(const f32x4*)&xr[kt * 32], *(const f32x4*)&xr[kt * 32 + 4],
                    xh, xl);
      aH0 = __builtin_amdgcn_mfma_f32_16x16x32_f16(W1f[0][kt], xh, aH0, 0, 0, 0);
      aH1 = __builtin_amdgcn_mfma_f32_16x16x32_f16(W1f[1][kt], xh, aH1, 0, 0, 0);
      aL0 = __builtin_amdgcn_mfma_f32_16x16x32_f16(W1f[0][kt], xl, aL0, 0, 0, 0);
      aL1 = __builtin_amdgcn_mfma_f32_16x16x32_f16(W1f[1][kt], xl, aL1, 0, 0, 0);
    }
    {
      u32x2 pk0, pk1;
      pk0[0] = pk2_f16(ftanh(aH0[0] + aL0[0]), ftanh(aH0[1] + aL0[1]));
      pk0[1] = pk2_f16(ftanh(aH0[2] + aL0[2]), ftanh(aH0[3] + aL0[3]));
      pk1[0] = pk2_f16(ftanh(aH1[0] + aL1[0]), ftanh(aH1[1] + aL1[1]));
      pk1[1] = pk2_f16(ftanh(aH1[2] + aL1[2]), ftanh(aH1[3] + aL1[3]));
      *(u32x2*)&hb[it & 1][rowf][(2 * w + 0) * 8 + kg * 2] = pk0;
      *(u32x2*)&hb[it & 1][rowf][(2 * w + 1) * 8 + kg * 2] = pk1;
    }
    SCAN_BAR();

    #pragma unroll
    for (int tm = 0; tm < 2; ++tm) {
      f32x4 a2 = {b2r[tm][0], b2r[tm][1], b2r[tm][2], b2r[tm][3]};
      #pragma unroll
      for (int kt = 0; kt < 4; ++kt) {
        const u32x4 hp = *(const u32x4*)&hb[it & 1][rowf][kt * 16 + kg * 4];
        a2 = __builtin_amdgcn_mfma_f32_16x16x32_f16(W2f[tm][kt],
                 __builtin_bit_cast(half8, hp), a2, 0, 0, 0);
      }
      f32x4 ov;
      #pragma unroll
      for (int j = 0; j < 4; ++j) ov[j] = ftanh(a2[j]);
      *(f32x4*)&zs[((size_t)b * TT + t) * DZc + (2 * w + tm) * 16 + kg * 4] = ov;
    }
  }
}

// =====================================================================
// Fused scan+decoder (R11 = R8 revert + f32x2-packed basis + alphas in
// SGPR). R8's validated structure: GRP=16, grid 656, 2 lgkm-only
// barriers/step, no setprio, decoder fused at 1-step lag.
// Basis phase expressed as row-pair f32x2 arithmetic so the compiler
// can emit v_pk_* (bit-identical math, ~half the issue slots).
// =====================================================================
__global__ __launch_bounds__(256, 1) void scan_dec_kernel(
    const float* __restrict__ AW, const float* __restrict__ z0,
    const float* __restrict__ hvec, const float* __restrict__ alphas,
    const float* __restrict__ thetas,
    const float* __restrict__ dw1, const float* __restrict__ db1,
    const float* __restrict__ dw2, const float* __restrict__ db2,
    float* __restrict__ zs, float* __restrict__ xp)
{
  const int bid = blockIdx.x;
  const int g = bid & 15;
  const int s = bid >> 4;
  const int t0 = s * TAUc;
  const int nsteps = (s == NSEG - 1) ? (TT - t0) : TAUc;

  const int tid = threadIdx.x;
  const int w = tid >> 6, l = tid & 63;
  const int rowf = l & 15;
  const int kg = l >> 4;

  __shared__ float zbuf[DZc][20];          // [comp][row] for basis
  __shared__ float meanp[16][4];
  __shared__ unsigned pbuf[16][DZc + 4];   // basis packed bf16, pitch 132
  __shared__ unsigned zpkh[16][68];        // z f16 hi pairs
  __shared__ unsigned zpkl[16][68];        // z f16 lo pairs
  __shared__ unsigned hbuf[16][68];        // dec hidden f16 pairs

  // ---- recurrence stationary: W bf16 hi/lo frags, diag, h ----
  short8 Whi[2][4], Wlo[2][4];
  #pragma unroll
  for (int tm = 0; tm < 2; ++tm) {
    const int m = (2 * w + tm) * 16 + rowf;
    #pragma unroll
    for (int kt = 0; kt < 4; ++kt) {
      const int kb = kt * 32 + kg * 8;
      float f[8];
      #pragma unroll
      for (int i = 0; i < 8; ++i) {
        const int k = kb + i;
        f[i] = (k == m) ? 0.f : AW[m * DZc + k];
      }
      pack_hilo8(*(const f32x4*)&f[0], *(const f32x4*)&f[4],
                 Whi[tm][kt], Wlo[tm][kt]);
    }
  }
  float a_d[2][4], h_d[2][4];
  #pragma unroll
  for (int tm = 0; tm < 2; ++tm)
    #pragma unroll
    for (int j = 0; j < 4; ++j) {
      const int comp = (2 * w + tm) * 16 + kg * 4 + j;
      a_d[tm][j] = AW[comp * DZc + comp];
      h_d[tm][j] = hvec[comp];
    }

  // ---- decoder stationary: f16 weights ----
  half8 D1f[2][4], D2f[4];
  #pragma unroll
  for (int tm = 0; tm < 2; ++tm) {
    const int m = (2 * w + tm) * 16 + rowf;
    #pragma unroll
    for (int kt = 0; kt < 4; ++kt) {
      const int k0 = kt * 32 + kg * 8;
      D1f[tm][kt] = cvt8_f16(*(const f32x4*)&dw1[m * DZc + k0],
                             *(const f32x4*)&dw1[m * DZc + k0 + 4]);
    }
  }
  {
    const int m2 = w * 16 + rowf;
    #pragma unroll
    for (int kt = 0; kt < 4; ++kt) {
      const int k0 = kt * 32 + kg * 8;
      D2f[kt] = cvt8_f16(*(const f32x4*)&dw2[m2 * DZc + k0],
                         *(const f32x4*)&dw2[m2 * DZc + k0 + 4]);
    }
  }
  float d1b[2][4], d2b[4];
  #pragma unroll
  for (int tm = 0; tm < 2; ++tm)
    #pragma unroll
    for (int j = 0; j < 4; ++j)
      d1b[tm][j] = db1[(2 * w + tm) * 16 + kg * 4 + j];
  #pragma unroll
  for (int j = 0; j < 4; ++j)
    d2b[j] = db2[w * 16 + kg * 4 + j];

  // ---- basis-lane stationary: comp cb, rows rh*8..+7 ----
  const int cb = tid >> 1;
  const int rh = tid & 1;
  float th[DBc], al[DBc];
  #pragma unroll
  for (int d = 0; d < DBc; ++d) {
    th[d] = thetas[cb * DBc + d];
    al[d] = sload(&alphas[d]);             // uniform -> SGPR
  }

  const int brow = g * GRP + rowf;
  const size_t zb_row = (size_t)brow * TT * DZc;
  const size_t xp_row = (size_t)brow * TT * DXc;
  f32x4 z[2];
  #pragma unroll
  for (int tm = 0; tm < 2; ++tm) {
    const int comp0 = (2 * w + tm) * 16 + kg * 4;
    if (s == 0) z[tm] = *(const f32x4*)&z0[brow * DZc + comp0];
    else        z[tm] = *(const f32x4*)&zs[zb_row + (size_t)t0 * DZc + comp0];
  }

#define PUB_ZPK() do { \
    _Pragma("unroll") \
    for (int tm = 0; tm < 2; ++tm) { \
      u32x2 zh_, zl_; \
      pk4_f16_hilo(z[tm], zh_, zl_); \
      *(u32x2*)&zpkh[rowf][(2 * w + tm) * 8 + kg * 2] = zh_; \
      *(u32x2*)&zpkl[rowf][(2 * w + tm) * 8 + kg * 2] = zl_; \
    } } while (0)

#define DEC_L1() do { \
    f32x4 dAh = {d1b[0][0], d1b[0][1], d1b[0][2], d1b[0][3]}; \
    f32x4 dBh = {d1b[1][0], d1b[1][1], d1b[1][2], d1b[1][3]}; \
    f32x4 dAl = {0.f, 0.f, 0.f, 0.f}, dBl = {0.f, 0.f, 0.f, 0.f}; \
    _Pragma("unroll") \
    for (int kt = 0; kt < 4; ++kt) { \
      const u32x4 bh = *(const u32x4*)&zpkh[rowf][kt * 16 + kg * 4]; \
      const u32x4 bl = *(const u32x4*)&zpkl[rowf][kt * 16 + kg * 4]; \
      const half8 Bh = __builtin_bit_cast(half8, bh); \
      const half8 Bl = __builtin_bit_cast(half8, bl); \
      dAh = __builtin_amdgcn_mfma_f32_16x16x32_f16(D1f[0][kt], Bh, dAh, 0, 0, 0); \
      dBh = __builtin_amdgcn_mfma_f32_16x16x32_f16(D1f[1][kt], Bh, dBh, 0, 0, 0); \
      dAl = __builtin_amdgcn_mfma_f32_16x16x32_f16(D1f[0][kt], Bl, dAl, 0, 0, 0); \
      dBl = __builtin_amdgcn_mfma_f32_16x16x32_f16(D1f[1][kt], Bl, dBl, 0, 0, 0); \
    } \
    u32x2 pk0, pk1; \
    pk0[0] = pk2_f16(ftanh(dAh[0] + dAl[0]), ftanh(dAh[1] + dAl[1])); \
    pk0[1] = pk2_f16(ftanh(dAh[2] + dAl[2]), ftanh(dAh[3] + dAl[3])); \
    pk1[0] = pk2_f16(ftanh(dBh[0] + dBl[0]), ftanh(dBh[1] + dBl[1])); \
    pk1[1] = pk2_f16(ftanh(dBh[2] + dBl[2]), ftanh(dBh[3] + dBl[3])); \
    *(u32x2*)&hbuf[rowf][(2 * w + 0) * 8 + kg * 2] = pk0; \
    *(u32x2*)&hbuf[rowf][(2 * w + 1) * 8 + kg * 2] = pk1; \
    } while (0)

#define DEC_L2(TD) do { \
    f32x4 a2 = {d2b[0], d2b[1], d2b[2], d2b[3]}; \
    _Pragma("unroll") \
    for (int kt = 0; kt < 4; ++kt) { \
      const u32x4 hp = *(const u32x4*)&hbuf[rowf][kt * 16 + kg * 4]; \
      a2 = __builtin_amdgcn_mfma_f32_16x16x32_f16(D2f[kt], \
               __builtin_bit_cast(half8, hp), a2, 0, 0, 0); \
    } \
    f32x4 ov; \
    _Pragma("unroll") \
    for (int j = 0; j < 4; ++j) ov[j] = ftanh(a2[j]); \
    *(f32x4*)&xp[xp_row + (size_t)(TD) * DXc + w * 16 + kg * 4] = ov; \
    } while (0)

  for (int it = 0; it < nsteps; ++it) {
    const int t = t0 + it;

    // ---- Phase A: publish z ----
    float ssum = ((z[0][0] + z[0][1]) + (z[0][2] + z[0][3]))
               + ((z[1][0] + z[1][1]) + (z[1][2] + z[1][3]));
    ssum += __shfl_xor(ssum, 16, 64);
    ssum += __shfl_xor(ssum, 32, 64);
    if (l < 16) meanp[l][w] = ssum;
    #pragma unroll
    for (int tm = 0; tm < 2; ++tm)
      #pragma unroll
      for (int j = 0; j < 4; ++j)
        zbuf[(2 * w + tm) * 16 + kg * 4 + j][rowf] = z[tm][j];
    PUB_ZPK();
    SCAN_BAR();

    // ---- Phase B: basis (f32x2 row-pairs) + decode-L1 (z_seq[t-1]) ----
    {
      float zr[8], mean[8];
      *(f32x4*)&zr[0] = *(const f32x4*)&zbuf[cb][rh * 8];
      *(f32x4*)&zr[4] = *(const f32x4*)&zbuf[cb][rh * 8 + 4];
      #pragma unroll
      for (int q = 0; q < 8; ++q) {
        const f32x4 mp = *(const f32x4*)&meanp[rh * 8 + q][0];
        mean[q] = ((mp[0] + mp[1]) + (mp[2] + mp[3])) * (1.0f / 128.0f);
      }
      #pragma unroll
      for (int qp = 0; qp < 4; ++qp) {
        f32x2 zc2;
        zc2[0] = zr[2 * qp]     - mean[2 * qp];
        zc2[1] = zr[2 * qp + 1] - mean[2 * qp + 1];
        f32x2 bs2 = {0.f, 0.f};
        #pragma unroll
        for (int d = 0; d < DBc; ++d) {
          const f32x2 th2 = {th[d], th[d]};
          const f32x2 al2 = {al[d], al[d]};
          const f32x2 zer = {0.f, 0.f};
          bs2 = __builtin_elementwise_fma(
                  al2, __builtin_elementwise_max(zc2 + th2, zer), bs2);
        }
        #pragma unroll
        for (int e = 0; e < 2; ++e) {
          const float bs = bs2[e];
          const unsigned fb = __float_as_uint(bs);
          const float lof = bs - __uint_as_float(fb & 0xFFFF0000u);
          const unsigned pk = perm_b32(__float_as_uint(lof), fb, 0x07060302u);
          pbuf[rh * 8 + 2 * qp + e][cb] = pk;
        }
      }
    }
    if (it > 0) DEC_L1();
    SCAN_BAR();

    // ---- Phase C: decode-L2 + recurrence ----
    if (it > 0) DEC_L2(t - 1);
    {
      f32x4 acc1[2], acc2[2];
      #pragma unroll
      for (int tm = 0; tm < 2; ++tm)
        #pragma unroll
        for (int j = 0; j < 4; ++j) {
          acc1[tm][j] = fmaf(a_d[tm][j], z[tm][j], h_d[tm][j]);
          acc2[tm][j] = 0.f;
        }
      #pragma unroll
      for (int kt = 0; kt < 4; ++kt) {
        const int cbase = kt * 32 + kg * 8;
        const u32x4 p0 = *(const u32x4*)&pbuf[rowf][cbase];
        const u32x4 p1 = *(const u32x4*)&pbuf[rowf][cbase + 4];
        u32x4 hi4, lo4;
        hi4[0] = perm_b32(p0[1], p0[0], 0x05040100u);
        hi4[1] = perm_b32(p0[3], p0[2], 0x05040100u);
        hi4[2] = perm_b32(p1[1], p1[0], 0x05040100u);
        hi4[3] = perm_b32(p1[3], p1[2], 0x05040100u);
        lo4[0] = perm_b32(p0[1], p0[0], 0x07060302u);
        lo4[1] = perm_b32(p0[3], p0[2], 0x07060302u);
        lo4[2] = perm_b32(p1[1], p1[0], 0x07060302u);
        lo4[3] = perm_b32(p1[3], p1[2], 0x07060302u);
        const short8 Bhi = __builtin_bit_cast(short8, hi4);
        const short8 Blo = __builtin_bit_cast(short8, lo4);
        acc1[0] = __builtin_amdgcn_mfma_f32_16x16x32_bf16(Whi[0][kt], Bhi, acc1[0], 0, 0, 0);
        acc1[1] = __builtin_amdgcn_mfma_f32_16x16x32_bf16(Whi[1][kt], Bhi, acc1[1], 0, 0, 0);
        acc2[0] = __builtin_amdgcn_mfma_f32_16x16x32_bf16(Whi[0][kt], Blo, acc2[0], 0, 0, 0);
        acc2[0] = __builtin_amdgcn_mfma_f32_16x16x32_bf16(Wlo[0][kt], Bhi, acc2[0], 0, 0, 0);
        acc2[1] = __builtin_amdgcn_mfma_f32_16x16x32_bf16(Whi[1][kt], Blo, acc2[1], 0, 0, 0);
        acc2[1] = __builtin_amdgcn_mfma_f32_16x16x32_bf16(Wlo[1][kt], Bhi, acc2[1], 0, 0, 0);
      }
      #pragma unroll
      for (int tm = 0; tm < 2; ++tm) {
        f32x4 zn;
        #pragma unroll
        for (int j = 0; j < 4; ++j) {
          float v = acc1[tm][j] + acc2[tm][j];
          zn[j] = fminf(fmaxf(v, -CLIPV), CLIPV);
        }
        *(f32x4*)&zs[zb_row + (size_t)t * DZc + (2 * w + tm) * 16 + kg * 4] = zn;
        z[tm] = zn;
      }
    }
  }

  // ---- epilogue: decode the segment's final z_seq ----
  PUB_ZPK();
  SCAN_BAR();
  DEC_L1();
  SCAN_BAR();
  DEC_L2(t0 + nsteps - 1);

#undef PUB_ZPK
#undef DEC_L1
#undef DEC_L2
}

extern "C" void kernel_launch(void* const* d_in, const int* in_sizes, int n_in,
                              void* d_out, int out_size, void* d_ws, size_t ws_size,
                              hipStream_t stream) {
  const float* x      = (const float*)d_in[0];
  const float* z0     = (const float*)d_in[1];
  const float* AW     = (const float*)d_in[2];
  const float* hvec   = (const float*)d_in[3];
  const float* alphas = (const float*)d_in[4];
  const float* thetas = (const float*)d_in[5];
  const float* ew1    = (const float*)d_in[6];
  const float* eb1    = (const float*)d_in[7];
  const float* ew2    = (const float*)d_in[8];
  const float* eb2    = (const float*)d_in[9];
  const float* dw1    = (const float*)d_in[10];
  const float* db1    = (const float*)d_in[11];
  const float* dw2    = (const float*)d_in[12];
  const float* db2    = (const float*)d_in[13];

  float* xp = (float*)d_out;                       // (B,T,DX)
  float* zs = xp + (size_t)BB * TT * DXc;          // (B,T,DZ)

  // 1) MFMA encoder: 40 forcing steps -> stash into zs slots
  hipLaunchKernelGGL(enc_mfma_kernel,
                     dim3(NF * BB / (ENC_NT * 16)), dim3(256), 0, stream,
                     x, ew1, eb1, ew2, eb2, zs);

  // 2) fused scan + decoder: 16 row-groups x 41 segments = 656 blocks
  hipLaunchKernelGGL(scan_dec_kernel, dim3((BB / GRP) * NSEG), dim3(256), 0, stream,
                     AW, z0, hvec, alphas, thetas, dw1, db1, dw2, db2, zs, xp);
}

// Round 12
// 156.138 us; speedup vs baseline: 2.1180x; 1.2816x over previous
//
#include <hip/hip_runtime.h>
#include <hip/hip_bf16.h>

// ---- problem constants ----
constexpr int BB  = 256;   // batch
constexpr int TT  = 1024;  // timesteps
constexpr int DXc = 64;
constexpr int DZc = 128;
constexpr int DBc = 16;
constexpr int TAUc = 25;
constexpr float CLIPV = 10.0f;
constexpr int NF = 40;     // forcing steps: t = 25..1000
constexpr int NSEG = 41;   // independent scan segments (forcing breaks chain)
constexpr int GRP = 16;    // batch rows per scan block (MFMA N dim)

typedef __attribute__((ext_vector_type(8))) short short8;        // 8 bf16
typedef __attribute__((ext_vector_type(8))) _Float16 half8;      // 8 f16
typedef __attribute__((ext_vector_type(4))) float f32x4;
typedef __attribute__((ext_vector_type(4))) unsigned u32x4;
typedef __attribute__((ext_vector_type(2))) unsigned u32x2;

__device__ __forceinline__ unsigned perm_b32(unsigned a, unsigned b, unsigned s) {
  return __builtin_amdgcn_perm(a, b, s);
}

// pack 8 floats into bf16 hi + residual-lo short8 frags (W staging)
__device__ __forceinline__ void pack_hilo8(const f32x4 a, const f32x4 b,
                                           short8& hi, short8& lo) {
  float f[8];
  *(f32x4*)&f[0] = a;
  *(f32x4*)&f[4] = b;
  u32x4 hi4, lo4;
  #pragma unroll
  for (int p = 0; p < 4; ++p) {
    const unsigned b0 = __float_as_uint(f[2 * p]);
    const unsigned b1 = __float_as_uint(f[2 * p + 1]);
    hi4[p] = perm_b32(b1, b0, 0x07060302u);
    const float l0 = f[2 * p]     - __uint_as_float(b0 & 0xFFFF0000u);
    const float l1 = f[2 * p + 1] - __uint_as_float(b1 & 0xFFFF0000u);
    lo4[p] = perm_b32(__float_as_uint(l1), __float_as_uint(l0), 0x07060302u);
  }
  hi = __builtin_bit_cast(short8, hi4);
  lo = __builtin_bit_cast(short8, lo4);
}

// 8 floats -> f16 frag (RNE, single precision pass)
__device__ __forceinline__ half8 cvt8_f16(const f32x4 a, const f32x4 b) {
  float f[8];
  *(f32x4*)&f[0] = a;
  *(f32x4*)&f[4] = b;
  u32x4 h4;
  #pragma unroll
  for (int p = 0; p < 4; ++p) {
    const _Float16 h0 = (_Float16)f[2 * p], h1 = (_Float16)f[2 * p + 1];
    h4[p] = (unsigned)__builtin_bit_cast(unsigned short, h0)
          | ((unsigned)__builtin_bit_cast(unsigned short, h1) << 16);
  }
  return __builtin_bit_cast(half8, h4);
}

// 8 floats -> f16 hi + f16 residual frags
__device__ __forceinline__ void cvt8_f16_hilo(const f32x4 a, const f32x4 b,
                                              half8& hi, half8& lo) {
  float f[8];
  *(f32x4*)&f[0] = a;
  *(f32x4*)&f[4] = b;
  u32x4 h4, l4;
  #pragma unroll
  for (int p = 0; p < 4; ++p) {
    const float f0 = f[2 * p], f1 = f[2 * p + 1];
    const _Float16 h0 = (_Float16)f0, h1 = (_Float16)f1;
    const float r0 = f0 - (float)h0, r1 = f1 - (float)h1;
    const _Float16 e0 = (_Float16)r0, e1 = (_Float16)r1;
    h4[p] = (unsigned)__builtin_bit_cast(unsigned short, h0)
          | ((unsigned)__builtin_bit_cast(unsigned short, h1) << 16);
    l4[p] = (unsigned)__builtin_bit_cast(unsigned short, e0)
          | ((unsigned)__builtin_bit_cast(unsigned short, e1) << 16);
  }
  hi = __builtin_bit_cast(half8, h4);
  lo = __builtin_bit_cast(half8, l4);
}

__device__ __forceinline__ unsigned pk2_f16(float a, float b) {
  const _Float16 ha = (_Float16)a, hb = (_Float16)b;
  return (unsigned)__builtin_bit_cast(unsigned short, ha)
       | ((unsigned)__builtin_bit_cast(unsigned short, hb) << 16);
}

// f32x4 -> f16 hi pair-words + f16 residual pair-words
__device__ __forceinline__ void pk4_f16_hilo(const f32x4 v, u32x2& hi, u32x2& lo) {
  const _Float16 h0 = (_Float16)v[0], h1 = (_Float16)v[1];
  const _Float16 h2 = (_Float16)v[2], h3 = (_Float16)v[3];
  const float r0 = v[0] - (float)h0, r1 = v[1] - (float)h1;
  const float r2 = v[2] - (float)h2, r3 = v[3] - (float)h3;
  hi[0] = (unsigned)__builtin_bit_cast(unsigned short, h0)
        | ((unsigned)__builtin_bit_cast(unsigned short, h1) << 16);
  hi[1] = (unsigned)__builtin_bit_cast(unsigned short, h2)
        | ((unsigned)__builtin_bit_cast(unsigned short, h3) << 16);
  lo[0] = pk2_f16(r0, r1);
  lo[1] = pk2_f16(r2, r3);
}

// fast tanh: 1 - 2/(1+exp2(2x*log2e)), copysign. ~6 VALU, ~1e-6 rel err.
__device__ __forceinline__ float ftanh(float x) {
  const float ax = __builtin_fabsf(x);
  const float p  = __builtin_amdgcn_exp2f(ax * 2.8853900817779268f);
  const float r  = __builtin_amdgcn_rcpf(p + 1.0f);
  const float t  = __builtin_fmaf(-2.0f, r, 1.0f);
  return __builtin_copysignf(t, x);
}

#define SCAN_BAR() do { \
    __asm__ volatile("s_waitcnt lgkmcnt(0)" ::: "memory"); \
    __builtin_amdgcn_s_barrier(); \
    __asm__ volatile("" ::: "memory"); } while (0)

// =====================================================================
// Encoder (MFMA): 10240 gathered rows (40 forcing steps x 256 batch),
// 64->128->128 tanh MLP, f16-stationary weights, x in f16 hi+lo.
// Output stashed into zs forcing slots. Grid 160 x 4 waves.
// =====================================================================
constexpr int ENC_NT = 4;

__global__ __launch_bounds__(256, 2) void enc_mfma_kernel(
    const float* __restrict__ x, const float* __restrict__ w1,
    const float* __restrict__ b1v, const float* __restrict__ w2,
    const float* __restrict__ b2v, float* __restrict__ zs)
{
  const int tid = threadIdx.x;
  const int w = tid >> 6, l = tid & 63;
  const int rowf = l & 15;
  const int kg = l >> 4;

  __shared__ unsigned hb[2][16][68];

  half8 W1f[2][2], W2f[2][4];
  #pragma unroll
  for (int tm = 0; tm < 2; ++tm) {
    const int m = (2 * w + tm) * 16 + rowf;
    #pragma unroll
    for (int kt = 0; kt < 2; ++kt) {             // K = 64
      const int k0 = kt * 32 + kg * 8;
      W1f[tm][kt] = cvt8_f16(*(const f32x4*)&w1[m * DXc + k0],
                             *(const f32x4*)&w1[m * DXc + k0 + 4]);
    }
    #pragma unroll
    for (int kt = 0; kt < 4; ++kt) {             // K = 128
      const int k0 = kt * 32 + kg * 8;
      W2f[tm][kt] = cvt8_f16(*(const f32x4*)&w2[m * DZc + k0],
                             *(const f32x4*)&w2[m * DZc + k0 + 4]);
    }
  }
  float b1r[2][4], b2r[2][4];
  #pragma unroll
  for (int tm = 0; tm < 2; ++tm)
    #pragma unroll
    for (int j = 0; j < 4; ++j) {
      b1r[tm][j] = b1v[(2 * w + tm) * 16 + kg * 4 + j];
      b2r[tm][j] = b2v[(2 * w + tm) * 16 + kg * 4 + j];
    }

  for (int it = 0; it < ENC_NT; ++it) {
    const int r = blockIdx.x * (ENC_NT * 16) + it * 16 + rowf;
    const int f = r >> 8, b = r & 255;
    const int t = TAUc * (f + 1);
    const float* xr = x + ((size_t)b * TT + t) * DXc + kg * 8;

    f32x4 aH0 = {b1r[0][0], b1r[0][1], b1r[0][2], b1r[0][3]};
    f32x4 aH1 = {b1r[1][0], b1r[1][1], b1r[1][2], b1r[1][3]};
    f32x4 aL0 = {0.f, 0.f, 0.f, 0.f}, aL1 = {0.f, 0.f, 0.f, 0.f};
    #pragma unroll
    for (int kt = 0; kt < 2; ++kt) {
      half8 xh, xl;
      cvt8_f16_hilo(*(const f32x4*)&xr[kt * 32], *(const f32x4*)&xr[kt * 32 + 4],
                    xh, xl);
      aH0 = __builtin_amdgcn_mfma_f32_16x16x32_f16(W1f[0][kt], xh, aH0, 0, 0, 0);
      aH1 = __builtin_amdgcn_mfma_f32_16x16x32_f16(W1f[1][kt], xh, aH1, 0, 0, 0);
      aL0 = __builtin_amdgcn_mfma_f32_16x16x32_f16(W1f[0][kt], xl, aL0, 0, 0, 0);
      aL1 = __builtin_amdgcn_mfma_f32_16x16x32_f16(W1f[1][kt], xl, aL1, 0, 0, 0);
    }
    {
      u32x2 pk0, pk1;
      pk0[0] = pk2_f16(ftanh(aH0[0] + aL0[0]), ftanh(aH0[1] + aL0[1]));
      pk0[1] = pk2_f16(ftanh(aH0[2] + aL0[2]), ftanh(aH0[3] + aL0[3]));
      pk1[0] = pk2_f16(ftanh(aH1[0] + aL1[0]), ftanh(aH1[1] + aL1[1]));
      pk1[1] = pk2_f16(ftanh(aH1[2] + aL1[2]), ftanh(aH1[3] + aL1[3]));
      *(u32x2*)&hb[it & 1][rowf][(2 * w + 0) * 8 + kg * 2] = pk0;
      *(u32x2*)&hb[it & 1][rowf][(2 * w + 1) * 8 + kg * 2] = pk1;
    }
    SCAN_BAR();

    #pragma unroll
    for (int tm = 0; tm < 2; ++tm) {
      f32x4 a2 = {b2r[tm][0], b2r[tm][1], b2r[tm][2], b2r[tm][3]};
      #pragma unroll
      for (int kt = 0; kt < 4; ++kt) {
        const u32x4 hp = *(const u32x4*)&hb[it & 1][rowf][kt * 16 + kg * 4];
        a2 = __builtin_amdgcn_mfma_f32_16x16x32_f16(W2f[tm][kt],
                 __builtin_bit_cast(half8, hp), a2, 0, 0, 0);
      }
      f32x4 ov;
      #pragma unroll
      for (int j = 0; j < 4; ++j) ov[j] = ftanh(a2[j]);
      *(f32x4*)&zs[((size_t)b * TT + t) * DZc + (2 * w + tm) * 16 + kg * 4] = ov;
    }
  }
}

// =====================================================================
// Fused scan+decoder: EXACT R8 configuration (measured 156 µs, VGPR
// 128, zero scratch). 16 batch rows x 41 segments (grid 656, 4 waves).
// Recurrence bf16 hi/lo 3-term MFMA; decoder f16-stationary, fused at
// 1-step lag with zero extra in-loop barriers; 2 lgkm-only barriers
// per step. R9/R10/R11 peripheral changes (setprio, GRP=8, packed
// basis, sload alphas) all regressed via the 128-VGPR occupancy cliff
// — do not touch the register allocation equilibrium.
// =====================================================================
__global__ __launch_bounds__(256, 1) void scan_dec_kernel(
    const float* __restrict__ AW, const float* __restrict__ z0,
    const float* __restrict__ hvec, const float* __restrict__ alphas,
    const float* __restrict__ thetas,
    const float* __restrict__ dw1, const float* __restrict__ db1,
    const float* __restrict__ dw2, const float* __restrict__ db2,
    float* __restrict__ zs, float* __restrict__ xp)
{
  const int bid = blockIdx.x;
  const int g = bid & 15;
  const int s = bid >> 4;
  const int t0 = s * TAUc;
  const int nsteps = (s == NSEG - 1) ? (TT - t0) : TAUc;

  const int tid = threadIdx.x;
  const int w = tid >> 6, l = tid & 63;
  const int rowf = l & 15;
  const int kg = l >> 4;

  __shared__ float zbuf[DZc][20];
  __shared__ float meanp[16][4];
  __shared__ unsigned pbuf[16][DZc + 4];   // pitch 132
  __shared__ unsigned zpkh[16][68];
  __shared__ unsigned zpkl[16][68];
  __shared__ unsigned hbuf[16][68];

  short8 Whi[2][4], Wlo[2][4];
  #pragma unroll
  for (int tm = 0; tm < 2; ++tm) {
    const int m = (2 * w + tm) * 16 + rowf;
    #pragma unroll
    for (int kt = 0; kt < 4; ++kt) {
      const int kb = kt * 32 + kg * 8;
      float f[8];
      #pragma unroll
      for (int i = 0; i < 8; ++i) {
        const int k = kb + i;
        f[i] = (k == m) ? 0.f : AW[m * DZc + k];
      }
      pack_hilo8(*(const f32x4*)&f[0], *(const f32x4*)&f[4],
                 Whi[tm][kt], Wlo[tm][kt]);
    }
  }
  float a_d[2][4], h_d[2][4];
  #pragma unroll
  for (int tm = 0; tm < 2; ++tm)
    #pragma unroll
    for (int j = 0; j < 4; ++j) {
      const int comp = (2 * w + tm) * 16 + kg * 4 + j;
      a_d[tm][j] = AW[comp * DZc + comp];
      h_d[tm][j] = hvec[comp];
    }

  half8 D1f[2][4], D2f[4];
  #pragma unroll
  for (int tm = 0; tm < 2; ++tm) {
    const int m = (2 * w + tm) * 16 + rowf;
    #pragma unroll
    for (int kt = 0; kt < 4; ++kt) {
      const int k0 = kt * 32 + kg * 8;
      D1f[tm][kt] = cvt8_f16(*(const f32x4*)&dw1[m * DZc + k0],
                             *(const f32x4*)&dw1[m * DZc + k0 + 4]);
    }
  }
  {
    const int m2 = w * 16 + rowf;
    #pragma unroll
    for (int kt = 0; kt < 4; ++kt) {
      const int k0 = kt * 32 + kg * 8;
      D2f[kt] = cvt8_f16(*(const f32x4*)&dw2[m2 * DZc + k0],
                         *(const f32x4*)&dw2[m2 * DZc + k0 + 4]);
    }
  }
  float d1b[2][4], d2b[4];
  #pragma unroll
  for (int tm = 0; tm < 2; ++tm)
    #pragma unroll
    for (int j = 0; j < 4; ++j)
      d1b[tm][j] = db1[(2 * w + tm) * 16 + kg * 4 + j];
  #pragma unroll
  for (int j = 0; j < 4; ++j)
    d2b[j] = db2[w * 16 + kg * 4 + j];

  const int cb = tid >> 1;
  const int rh = tid & 1;
  float th[DBc], al[DBc];
  #pragma unroll
  for (int d = 0; d < DBc; ++d) {
    th[d] = thetas[cb * DBc + d];
    al[d] = alphas[d];
  }

  const int brow = g * GRP + rowf;
  const size_t zb_row = (size_t)brow * TT * DZc;
  const size_t xp_row = (size_t)brow * TT * DXc;
  f32x4 z[2];
  #pragma unroll
  for (int tm = 0; tm < 2; ++tm) {
    const int comp0 = (2 * w + tm) * 16 + kg * 4;
    if (s == 0) z[tm] = *(const f32x4*)&z0[brow * DZc + comp0];
    else        z[tm] = *(const f32x4*)&zs[zb_row + (size_t)t0 * DZc + comp0];
  }

#define PUB_ZPK() do { \
    _Pragma("unroll") \
    for (int tm = 0; tm < 2; ++tm) { \
      u32x2 zh_, zl_; \
      pk4_f16_hilo(z[tm], zh_, zl_); \
      *(u32x2*)&zpkh[rowf][(2 * w + tm) * 8 + kg * 2] = zh_; \
      *(u32x2*)&zpkl[rowf][(2 * w + tm) * 8 + kg * 2] = zl_; \
    } } while (0)

#define DEC_L1() do { \
    f32x4 dAh = {d1b[0][0], d1b[0][1], d1b[0][2], d1b[0][3]}; \
    f32x4 dBh = {d1b[1][0], d1b[1][1], d1b[1][2], d1b[1][3]}; \
    f32x4 dAl = {0.f, 0.f, 0.f, 0.f}, dBl = {0.f, 0.f, 0.f, 0.f}; \
    _Pragma("unroll") \
    for (int kt = 0; kt < 4; ++kt) { \
      const u32x4 bh = *(const u32x4*)&zpkh[rowf][kt * 16 + kg * 4]; \
      const u32x4 bl = *(const u32x4*)&zpkl[rowf][kt * 16 + kg * 4]; \
      const half8 Bh = __builtin_bit_cast(half8, bh); \
      const half8 Bl = __builtin_bit_cast(half8, bl); \
      dAh = __builtin_amdgcn_mfma_f32_16x16x32_f16(D1f[0][kt], Bh, dAh, 0, 0, 0); \
      dBh = __builtin_amdgcn_mfma_f32_16x16x32_f16(D1f[1][kt], Bh, dBh, 0, 0, 0); \
      dAl = __builtin_amdgcn_mfma_f32_16x16x32_f16(D1f[0][kt], Bl, dAl, 0, 0, 0); \
      dBl = __builtin_amdgcn_mfma_f32_16x16x32_f16(D1f[1][kt], Bl, dBl, 0, 0, 0); \
    } \
    u32x2 pk0, pk1; \
    pk0[0] = pk2_f16(ftanh(dAh[0] + dAl[0]), ftanh(dAh[1] + dAl[1])); \
    pk0[1] = pk2_f16(ftanh(dAh[2] + dAl[2]), ftanh(dAh[3] + dAl[3])); \
    pk1[0] = pk2_f16(ftanh(dBh[0] + dBl[0]), ftanh(dBh[1] + dBl[1])); \
    pk1[1] = pk2_f16(ftanh(dBh[2] + dBl[2]), ftanh(dBh[3] + dBl[3])); \
    *(u32x2*)&hbuf[rowf][(2 * w + 0) * 8 + kg * 2] = pk0; \
    *(u32x2*)&hbuf[rowf][(2 * w + 1) * 8 + kg * 2] = pk1; \
    } while (0)

#define DEC_L2(TD) do { \
    f32x4 a2 = {d2b[0], d2b[1], d2b[2], d2b[3]}; \
    _Pragma("unroll") \
    for (int kt = 0; kt < 4; ++kt) { \
      const u32x4 hp = *(const u32x4*)&hbuf[rowf][kt * 16 + kg * 4]; \
      a2 = __builtin_amdgcn_mfma_f32_16x16x32_f16(D2f[kt], \
               __builtin_bit_cast(half8, hp), a2, 0, 0, 0); \
    } \
    f32x4 ov; \
    _Pragma("unroll") \
    for (int j = 0; j < 4; ++j) ov[j] = ftanh(a2[j]); \
    *(f32x4*)&xp[xp_row + (size_t)(TD) * DXc + w * 16 + kg * 4] = ov; \
    } while (0)

  for (int it = 0; it < nsteps; ++it) {
    const int t = t0 + it;

    // Phase A
    float ssum = ((z[0][0] + z[0][1]) + (z[0][2] + z[0][3]))
               + ((z[1][0] + z[1][1]) + (z[1][2] + z[1][3]));
    ssum += __shfl_xor(ssum, 16, 64);
    ssum += __shfl_xor(ssum, 32, 64);
    if (l < 16) meanp[l][w] = ssum;
    #pragma unroll
    for (int tm = 0; tm < 2; ++tm)
      #pragma unroll
      for (int j = 0; j < 4; ++j)
        zbuf[(2 * w + tm) * 16 + kg * 4 + j][rowf] = z[tm][j];
    PUB_ZPK();
    SCAN_BAR();

    // Phase B: basis + decode-L1 (z_seq[t-1])
    {
      float zr[8], mean[8];
      *(f32x4*)&zr[0] = *(const f32x4*)&zbuf[cb][rh * 8];
      *(f32x4*)&zr[4] = *(const f32x4*)&zbuf[cb][rh * 8 + 4];
      #pragma unroll
      for (int q = 0; q < 8; ++q) {
        const f32x4 mp = *(const f32x4*)&meanp[rh * 8 + q][0];
        mean[q] = ((mp[0] + mp[1]) + (mp[2] + mp[3])) * (1.0f / 128.0f);
      }
      #pragma unroll
      for (int q = 0; q < 8; ++q) {
        const float zc = zr[q] - mean[q];
        float bs = 0.f;
        #pragma unroll
        for (int d = 0; d < DBc; ++d)
          bs = fmaf(al[d], fmaxf(zc + th[d], 0.f), bs);
        const unsigned fb = __float_as_uint(bs);
        const float lof = bs - __uint_as_float(fb & 0xFFFF0000u);
        const unsigned pk = perm_b32(__float_as_uint(lof), fb, 0x07060302u);
        pbuf[rh * 8 + q][cb] = pk;
      }
    }
    if (it > 0) DEC_L1();
    SCAN_BAR();

    // Phase C: decode-L2 + recurrence
    if (it > 0) DEC_L2(t - 1);
    {
      f32x4 acc1[2], acc2[2];
      #pragma unroll
      for (int tm = 0; tm < 2; ++tm)
        #pragma unroll
        for (int j = 0; j < 4; ++j) {
          acc1[tm][j] = fmaf(a_d[tm][j], z[tm][j], h_d[tm][j]);
          acc2[tm][j] = 0.f;
        }
      #pragma unroll
      for (int kt = 0; kt < 4; ++kt) {
        const int cbase = kt * 32 + kg * 8;
        const u32x4 p0 = *(const u32x4*)&pbuf[rowf][cbase];
        const u32x4 p1 = *(const u32x4*)&pbuf[rowf][cbase + 4];
        u32x4 hi4, lo4;
        hi4[0] = perm_b32(p0[1], p0[0], 0x05040100u);
        hi4[1] = perm_b32(p0[3], p0[2], 0x05040100u);
        hi4[2] = perm_b32(p1[1], p1[0], 0x05040100u);
        hi4[3] = perm_b32(p1[3], p1[2], 0x05040100u);
        lo4[0] = perm_b32(p0[1], p0[0], 0x07060302u);
        lo4[1] = perm_b32(p0[3], p0[2], 0x07060302u);
        lo4[2] = perm_b32(p1[1], p1[0], 0x07060302u);
        lo4[3] = perm_b32(p1[3], p1[2], 0x07060302u);
        const short8 Bhi = __builtin_bit_cast(short8, hi4);
        const short8 Blo = __builtin_bit_cast(short8, lo4);
        acc1[0] = __builtin_amdgcn_mfma_f32_16x16x32_bf16(Whi[0][kt], Bhi, acc1[0], 0, 0, 0);
        acc1[1] = __builtin_amdgcn_mfma_f32_16x16x32_bf16(Whi[1][kt], Bhi, acc1[1], 0, 0, 0);
        acc2[0] = __builtin_amdgcn_mfma_f32_16x16x32_bf16(Whi[0][kt], Blo, acc2[0], 0, 0, 0);
        acc2[0] = __builtin_amdgcn_mfma_f32_16x16x32_bf16(Wlo[0][kt], Bhi, acc2[0], 0, 0, 0);
        acc2[1] = __builtin_amdgcn_mfma_f32_16x16x32_bf16(Whi[1][kt], Blo, acc2[1], 0, 0, 0);
        acc2[1] = __builtin_amdgcn_mfma_f32_16x16x32_bf16(Wlo[1][kt], Bhi, acc2[1], 0, 0, 0);
      }
      #pragma unroll
      for (int tm = 0; tm < 2; ++tm) {
        f32x4 zn;
        #pragma unroll
        for (int j = 0; j < 4; ++j) {
          float v = acc1[tm][j] + acc2[tm][j];
          zn[j] = fminf(fmaxf(v, -CLIPV), CLIPV);
        }
        *(f32x4*)&zs[zb_row + (size_t)t * DZc + (2 * w + tm) * 16 + kg * 4] = zn;
        z[tm] = zn;
      }
    }
  }

  // epilogue: decode final z_seq of this segment
  PUB_ZPK();
  SCAN_BAR();
  DEC_L1();
  SCAN_BAR();
  DEC_L2(t0 + nsteps - 1);

#undef PUB_ZPK
#undef DEC_L1
#undef DEC_L2
}

extern "C" void kernel_launch(void* const* d_in, const int* in_sizes, int n_in,
                              void* d_out, int out_size, void* d_ws, size_t ws_size,
                              hipStream_t stream) {
  const float* x      = (const float*)d_in[0];
  const float* z0     = (const float*)d_in[1];
  const float* AW     = (const float*)d_in[2];
  const float* hvec   = (const float*)d_in[3];
  const float* alphas = (const float*)d_in[4];
  const float* thetas = (const float*)d_in[5];
  const float* ew1    = (const float*)d_in[6];
  const float* eb1    = (const float*)d_in[7];
  const float* ew2    = (const float*)d_in[8];
  const float* eb2    = (const float*)d_in[9];
  const float* dw1    = (const float*)d_in[10];
  const float* db1    = (const float*)d_in[11];
  const float* dw2    = (const float*)d_in[12];
  const float* db2    = (const float*)d_in[13];

  float* xp = (float*)d_out;                       // (B,T,DX)
  float* zs = xp + (size_t)BB * TT * DXc;          // (B,T,DZ)

  // 1) MFMA encoder: 40 forcing steps -> stash into zs slots
  hipLaunchKernelGGL(enc_mfma_kernel,
                     dim3(NF * BB / (ENC_NT * 16)), dim3(256), 0, stream,
                     x, ew1, eb1, ew2, eb2, zs);

  // 2) fused scan + decoder
  hipLaunchKernelGGL(scan_dec_kernel, dim3((BB / GRP) * NSEG), dim3(256), 0, stream,
                     AW, z0, hvec, alphas, thetas, dw1, db1, dw2, db2, zs, xp);
}